// Round 1
// baseline (623.231 us; speedup 1.0000x reference)
//
#include <hip/hip_runtime.h>
#include <hip/hip_bf16.h>
#include <math.h>

// Problem constants (fixed by setup_inputs)
#define BB 4
#define TPP 4
#define TFF 2
#define NIMG (BB*TPP)   // 16
#define NF (BB*TFF)     // 8

// ---------------------------------------------------------------------------
// Tiny kernel: replicate _interp_indices on device + mark needed past frames.
// ---------------------------------------------------------------------------
__global__ void idx_kernel(const int* __restrict__ pci, const int* __restrict__ fci,
                           int* __restrict__ idx, int* __restrict__ needed)
{
    if (threadIdx.x == 0 && blockIdx.x == 0) {
        for (int n = 0; n < BB*TPP; n++) needed[n] = 0;
        for (int i = 0; i < BB; i++) {
            needed[i*TPP + TPP-1] = 1;              // f1 frame always needed
            int p_pos = TPP - 2;
            for (int j = 0; j < TFF; j++) {
                int f = fci[i*TFF + j];
                while (p_pos >= 0) {
                    if (p_pos == 0 || f < -pci[i*TPP + p_pos - 1]) {
                        idx[i*TFF + j] = p_pos + i*TPP;
                        needed[p_pos + i*TPP] = 1;
                        break;
                    }
                    p_pos--;
                }
            }
        }
    }
}

// ---------------------------------------------------------------------------
// Conv 1x1 + BN + SiLU as tiled SGEMM.  Y[n,d,p] = silu(bn(sum_c W[d,c] X[n,c,p]))
// Block: 256 threads, 64(d) x 64(p) tile, K-tile 16, 4x4 microtile per thread.
// ---------------------------------------------------------------------------
template<int C, int HW>
__global__ __launch_bounds__(256)
void conv_kernel(const float* __restrict__ x, const float* __restrict__ wmat,
                 const float* __restrict__ g, const float* __restrict__ bbias,
                 const float* __restrict__ mmean, const float* __restrict__ vvar,
                 const int* __restrict__ needed, float* __restrict__ pf)
{
    const int n = blockIdx.z;
    if (!needed[n]) return;

    __shared__ float As[16][64];   // [k][d]
    __shared__ float Bs[16][64];   // [k][p]

    const int tid = threadIdx.x;
    const int tx = tid & 15;       // p group
    const int ty = tid >> 4;       // d group
    const int d0 = blockIdx.y * 64;
    const int p0 = blockIdx.x * 64;

    const float* xn = x + (size_t)n * C * HW;

    float acc[4][4];
    #pragma unroll
    for (int j = 0; j < 4; j++)
        #pragma unroll
        for (int i = 0; i < 4; i++) acc[j][i] = 0.f;

    for (int c0 = 0; c0 < C; c0 += 16) {
        // stage A: w[d0+d][c0+kb..kb+3]
        {
            int d  = tid >> 2;
            int kb = (tid & 3) * 4;
            float4 a4 = *(const float4*)(wmat + (size_t)(d0 + d) * C + c0 + kb);
            As[kb+0][d] = a4.x; As[kb+1][d] = a4.y;
            As[kb+2][d] = a4.z; As[kb+3][d] = a4.w;
        }
        // stage B: x[n][c0+k][p0+pb..pb+3]
        {
            int k  = tid >> 4;
            int pb = (tid & 15) * 4;
            const float* src = xn + (size_t)(c0 + k) * HW + p0 + pb;
            float4 b4;
            if (p0 + pb + 3 < HW) {
                b4 = *(const float4*)src;
            } else {
                b4.x = (p0+pb+0 < HW) ? src[0] : 0.f;
                b4.y = (p0+pb+1 < HW) ? src[1] : 0.f;
                b4.z = (p0+pb+2 < HW) ? src[2] : 0.f;
                b4.w = (p0+pb+3 < HW) ? src[3] : 0.f;
            }
            *(float4*)&Bs[k][pb] = b4;
        }
        __syncthreads();
        #pragma unroll
        for (int k = 0; k < 16; k++) {
            float4 a4 = *(const float4*)&As[k][ty*4];
            float4 b4 = *(const float4*)&Bs[k][tx*4];
            const float* ap = &a4.x;
            const float* bp = &b4.x;
            #pragma unroll
            for (int j = 0; j < 4; j++)
                #pragma unroll
                for (int i = 0; i < 4; i++)
                    acc[j][i] = fmaf(ap[j], bp[i], acc[j][i]);
        }
        __syncthreads();
    }

    // epilogue: BN + SiLU, store
    #pragma unroll
    for (int j = 0; j < 4; j++) {
        int d = d0 + ty*4 + j;
        float sc = g[d] * rsqrtf(vvar[d] + 1e-5f);
        float sh = bbias[d] - mmean[d] * sc;
        #pragma unroll
        for (int i = 0; i < 4; i++) {
            int p = p0 + tx*4 + i;
            if (p < HW) {
                float y = acc[j][i] * sc + sh;
                float o = y / (1.f + __expf(-y));
                pf[((size_t)n * C + d) * HW + p] = o;
            }
        }
    }
}

// ---------------------------------------------------------------------------
// Fused local-corr(81 offsets) + softmax + mlp dot.  One block per (n, c).
// f1 (last past frame) zero-padded plane staged in LDS; f2 streamed from global.
// Each thread handles quads of 4 consecutive pixels; per (quad,ky) a contiguous
// window of 8*STEP+4 floats is loaded with float4 reads (always 16B aligned).
// ---------------------------------------------------------------------------
template<int C, int H, int W, int STEP>
__global__ __launch_bounds__(256)
void corr_kernel(const float* __restrict__ pf, const int* __restrict__ idx,
                 const float* __restrict__ mlp, float* __restrict__ out)
{
    constexpr int R   = 4;
    constexpr int PAD = R * STEP;
    constexpr int PW  = W + 2*PAD;
    constexpr int PH  = H + 2*PAD;
    constexpr int HW  = H * W;
    constexpr int NQ  = (HW/4 + 255) / 256;     // quads per thread
    constexpr int WIN = 8*STEP + 4;             // window floats per (quad,ky)

    __shared__ __align__(16) float f1s[PH*PW];
    __shared__ float wpart[4][81];
    __shared__ float simS[88];

    const int n   = blockIdx.y;   // b*TF + t
    const int c   = blockIdx.x;
    const int b   = n / TFF;
    const int tid = threadIdx.x;

    const float* f1 = pf + ((size_t)(b*TPP + TPP-1) * C + c) * HW;
    const float* f2 = pf + ((size_t)idx[n] * C + c) * HW;

    // stage padded f1 plane
    for (int i = tid; i < PH*PW; i += 256) {
        int y = i / PW - PAD;
        int x = i % PW - PAD;
        float val = 0.f;
        if (y >= 0 && y < H && x >= 0 && x < W) val = f1[y*W + x];
        f1s[i] = val;
    }
    __syncthreads();

    float acc[81];
    #pragma unroll
    for (int k = 0; k < 81; k++) acc[k] = 0.f;

    #pragma unroll
    for (int q = 0; q < NQ; q++) {
        int p4 = (tid + q*256) * 4;
        if (p4 < HW) {
            float4 fv = *(const float4*)(f2 + p4);
            int h  = p4 / W;
            int w0 = p4 % W;
            #pragma unroll
            for (int ky = 0; ky < 9; ky++) {
                const float* row = &f1s[(h + PAD + (ky-4)*STEP) * PW + w0];
                float win[WIN];
                #pragma unroll
                for (int t = 0; t < WIN/4; t++)
                    *(float4*)&win[t*4] = *(const float4*)&row[t*4];
                #pragma unroll
                for (int kx = 0; kx < 9; kx++) {
                    acc[ky*9+kx] = fmaf(win[kx*STEP+0], fv.x, acc[ky*9+kx]);
                    acc[ky*9+kx] = fmaf(win[kx*STEP+1], fv.y, acc[ky*9+kx]);
                    acc[ky*9+kx] = fmaf(win[kx*STEP+2], fv.z, acc[ky*9+kx]);
                    acc[ky*9+kx] = fmaf(win[kx*STEP+3], fv.w, acc[ky*9+kx]);
                }
            }
        }
    }

    // per-wave butterfly reduce each of the 81 sums
    const int wid  = tid >> 6;
    const int lane = tid & 63;
    #pragma unroll
    for (int k = 0; k < 81; k++) {
        float v = acc[k];
        v += __shfl_xor(v, 32);
        v += __shfl_xor(v, 16);
        v += __shfl_xor(v, 8);
        v += __shfl_xor(v, 4);
        v += __shfl_xor(v, 2);
        v += __shfl_xor(v, 1);
        if (lane == 0) wpart[wid][k] = v;
    }
    __syncthreads();
    if (tid < 81)
        simS[tid] = wpart[0][tid] + wpart[1][tid] + wpart[2][tid] + wpart[3][tid];
    __syncthreads();

    // softmax over 81 + dot with mlp weights, by wave 0
    if (tid < 64) {
        float v0 = simS[tid];
        float v1 = (tid + 64 < 81) ? simS[tid + 64] : -INFINITY;
        float mx = fmaxf(v0, v1);
        #pragma unroll
        for (int m = 32; m; m >>= 1) mx = fmaxf(mx, __shfl_xor(mx, m));
        float e0 = __expf(v0 - mx);
        float e1 = (tid + 64 < 81) ? __expf(v1 - mx) : 0.f;
        float s  = e0 + e1;
        float d  = e0 * mlp[tid] + ((tid + 64 < 81) ? e1 * mlp[tid + 64] : 0.f);
        #pragma unroll
        for (int m = 32; m; m >>= 1) { s += __shfl_xor(s, m); d += __shfl_xor(d, m); }
        if (tid == 0) out[(size_t)n * C + c] = d / s;
    }
}

// ---------------------------------------------------------------------------
extern "C" void kernel_launch(void* const* d_in, const int* in_sizes, int n_in,
                              void* d_out, int out_size, void* d_ws, size_t ws_size,
                              hipStream_t stream)
{
    const float* feat0 = (const float*)d_in[0];
    const float* w0 = (const float*)d_in[1];
    const float* g0 = (const float*)d_in[2];
    const float* b0 = (const float*)d_in[3];
    const float* m0 = (const float*)d_in[4];
    const float* v0 = (const float*)d_in[5];
    const float* feat1 = (const float*)d_in[6];
    const float* w1 = (const float*)d_in[7];
    const float* g1 = (const float*)d_in[8];
    const float* b1 = (const float*)d_in[9];
    const float* m1 = (const float*)d_in[10];
    const float* v1 = (const float*)d_in[11];
    const float* feat2 = (const float*)d_in[12];
    const float* w2 = (const float*)d_in[13];
    const float* g2 = (const float*)d_in[14];
    const float* b2 = (const float*)d_in[15];
    const float* m2 = (const float*)d_in[16];
    const float* v2 = (const float*)d_in[17];
    const float* mlp = (const float*)d_in[18];
    const int* pci = (const int*)d_in[19];
    const int* fci = (const int*)d_in[20];

    float* out = (float*)d_out;

    // workspace layout
    int* idxp    = (int*)d_ws;        // 8
    int* neededp = idxp + 8;          // 16
    float* pf0 = (float*)((char*)d_ws + 256);
    float* pf1 = pf0 + (size_t)NIMG * 128 * 6400;
    float* pf2 = pf1 + (size_t)NIMG * 256 * 1600;

    idx_kernel<<<1, 64, 0, stream>>>(pci, fci, idxp, neededp);

    // conv per level
    conv_kernel<128, 6400><<<dim3(100, 2, NIMG), 256, 0, stream>>>(
        feat0, w0, g0, b0, m0, v0, neededp, pf0);
    conv_kernel<256, 1600><<<dim3(25, 4, NIMG), 256, 0, stream>>>(
        feat1, w1, g1, b1, m1, v1, neededp, pf1);
    conv_kernel<512, 400><<<dim3(7, 8, NIMG), 256, 0, stream>>>(
        feat2, w2, g2, b2, m2, v2, neededp, pf2);

    // fused corr + softmax + mlp
    corr_kernel<128, 80, 80, 4><<<dim3(128, NF), 256, 0, stream>>>(
        pf0, idxp, mlp, out);
    corr_kernel<256, 40, 40, 2><<<dim3(256, NF), 256, 0, stream>>>(
        pf1, idxp, mlp, out + (size_t)NF * 128);
    corr_kernel<512, 20, 20, 1><<<dim3(512, NF), 256, 0, stream>>>(
        pf2, idxp, mlp, out + (size_t)NF * (128 + 256));
}

// Round 2
// 535.319 us; speedup vs baseline: 1.1642x; 1.1642x over previous
//
#include <hip/hip_runtime.h>
#include <hip/hip_bf16.h>
#include <math.h>

// Problem constants (fixed by setup_inputs)
#define BB 4
#define TPP 4
#define TFF 2
#define NIMG (BB*TPP)   // 16
#define NF (BB*TFF)     // 8

// ---------------------------------------------------------------------------
// Tiny kernel: replicate _interp_indices on device + mark needed past frames.
// ---------------------------------------------------------------------------
__global__ void idx_kernel(const int* __restrict__ pci, const int* __restrict__ fci,
                           int* __restrict__ idx, int* __restrict__ needed)
{
    if (threadIdx.x == 0 && blockIdx.x == 0) {
        for (int n = 0; n < BB*TPP; n++) needed[n] = 0;
        for (int i = 0; i < BB; i++) {
            needed[i*TPP + TPP-1] = 1;              // f1 frame always needed
            int p_pos = TPP - 2;
            for (int j = 0; j < TFF; j++) {
                int f = fci[i*TFF + j];
                while (p_pos >= 0) {
                    if (p_pos == 0 || f < -pci[i*TPP + p_pos - 1]) {
                        idx[i*TFF + j] = p_pos + i*TPP;
                        needed[p_pos + i*TPP] = 1;
                        break;
                    }
                    p_pos--;
                }
            }
        }
    }
}

// ---------------------------------------------------------------------------
// Conv 1x1 + BN + SiLU as tiled SGEMM.  Y[n,d,p] = silu(bn(sum_c W[d,c] X[n,c,p]))
// Block: 256 threads, 128(d) x 128(p) tile, K-tile 16, 8x8 microtile per thread
// in split-chunk form (two 4-wide chunks at +0/+64 -> 16B lane stride, no bank
// conflicts on ds_read_b128).  1 B LDS per FMA -> ~parity with VALU.
// ---------------------------------------------------------------------------
template<int C, int HW>
__global__ __launch_bounds__(256)
void conv_kernel(const float* __restrict__ x, const float* __restrict__ wmat,
                 const float* __restrict__ g, const float* __restrict__ bbias,
                 const float* __restrict__ mmean, const float* __restrict__ vvar,
                 const int* __restrict__ needed, float* __restrict__ pf)
{
    const int n = blockIdx.z;
    if (!needed[n]) return;

    __shared__ __align__(16) float As[16][128];   // [k][d]
    __shared__ __align__(16) float Bs[16][128];   // [k][p]

    const int tid = threadIdx.x;
    const int tx = tid & 15;       // p group
    const int ty = tid >> 4;       // d group
    const int d0 = blockIdx.y * 128;
    const int p0 = blockIdx.x * 128;

    const float* xn = x + (size_t)n * C * HW;

    float acc[8][8];
    #pragma unroll
    for (int j = 0; j < 8; j++)
        #pragma unroll
        for (int i = 0; i < 8; i++) acc[j][i] = 0.f;

    for (int c0 = 0; c0 < C; c0 += 16) {
        // stage A: w[d0+d][c0+kq..kq+7] -> As[k][d]   (transpose scatter)
        {
            int d  = tid >> 1;
            int kq = (tid & 1) * 8;
            const float* wsrc = wmat + (size_t)(d0 + d) * C + c0 + kq;
            float4 a0 = *(const float4*)(wsrc);
            float4 a1 = *(const float4*)(wsrc + 4);
            As[kq+0][d] = a0.x; As[kq+1][d] = a0.y;
            As[kq+2][d] = a0.z; As[kq+3][d] = a0.w;
            As[kq+4][d] = a1.x; As[kq+5][d] = a1.y;
            As[kq+6][d] = a1.z; As[kq+7][d] = a1.w;
        }
        // stage B: x[n][c0+k][p0 + tx*4 (+64)] -> Bs[k][...]
        {
            int k = tid >> 4;
            const float* src = xn + (size_t)(c0 + k) * HW;
            int pA = p0 + tx*4;
            int pB = p0 + 64 + tx*4;
            float4 b0, b1;
            if (pA + 3 < HW) b0 = *(const float4*)(src + pA);
            else {
                b0.x = (pA+0 < HW) ? src[pA+0] : 0.f;
                b0.y = (pA+1 < HW) ? src[pA+1] : 0.f;
                b0.z = (pA+2 < HW) ? src[pA+2] : 0.f;
                b0.w = (pA+3 < HW) ? src[pA+3] : 0.f;
            }
            if (pB + 3 < HW) b1 = *(const float4*)(src + pB);
            else {
                b1.x = (pB+0 < HW) ? src[pB+0] : 0.f;
                b1.y = (pB+1 < HW) ? src[pB+1] : 0.f;
                b1.z = (pB+2 < HW) ? src[pB+2] : 0.f;
                b1.w = (pB+3 < HW) ? src[pB+3] : 0.f;
            }
            *(float4*)&Bs[k][tx*4]      = b0;
            *(float4*)&Bs[k][64 + tx*4] = b1;
        }
        __syncthreads();
        #pragma unroll
        for (int k = 0; k < 16; k++) {
            float4 al = *(const float4*)&As[k][ty*4];
            float4 ah = *(const float4*)&As[k][64 + ty*4];
            float4 bl = *(const float4*)&Bs[k][tx*4];
            float4 bh = *(const float4*)&Bs[k][64 + tx*4];
            float a8[8] = {al.x, al.y, al.z, al.w, ah.x, ah.y, ah.z, ah.w};
            float b8[8] = {bl.x, bl.y, bl.z, bl.w, bh.x, bh.y, bh.z, bh.w};
            #pragma unroll
            for (int j = 0; j < 8; j++)
                #pragma unroll
                for (int i = 0; i < 8; i++)
                    acc[j][i] = fmaf(a8[j], b8[i], acc[j][i]);
        }
        __syncthreads();
    }

    // epilogue: BN + SiLU, store
    const bool full = (p0 + 128 <= HW);
    #pragma unroll
    for (int j = 0; j < 8; j++) {
        int d = d0 + ((j < 4) ? (ty*4 + j) : (64 + ty*4 + j - 4));
        float sc = g[d] * rsqrtf(vvar[d] + 1e-5f);
        float sh = bbias[d] - mmean[d] * sc;
        float* dst = pf + ((size_t)n * C + d) * HW;
        float o[8];
        #pragma unroll
        for (int i = 0; i < 8; i++) {
            float y = acc[j][i] * sc + sh;
            o[i] = y / (1.f + __expf(-y));
        }
        if (full) {
            *(float4*)&dst[p0 + tx*4]      = make_float4(o[0], o[1], o[2], o[3]);
            *(float4*)&dst[p0 + 64 + tx*4] = make_float4(o[4], o[5], o[6], o[7]);
        } else {
            #pragma unroll
            for (int i = 0; i < 8; i++) {
                int p = p0 + ((i < 4) ? (tx*4 + i) : (64 + tx*4 + i - 4));
                if (p < HW) dst[p] = o[i];
            }
        }
    }
}

// ---------------------------------------------------------------------------
// Fused local-corr(81 offsets) + softmax + mlp dot.
// One block per (b, c); both future frames handled together so each f1 window
// load from LDS feeds FMAs for BOTH frames (halves LDS bytes/FMA).
// 384 threads = 6 waves = (2 pixel halves) x (3 ky-triples): each wave owns
// only 3 ky -> acc[2][3][9] = 54 regs, leaving headroom for load pipelining.
// ---------------------------------------------------------------------------
template<int C, int H, int W, int STEP>
__global__ __launch_bounds__(384)
void corr_kernel(const float* __restrict__ pf, const int* __restrict__ idx,
                 const float* __restrict__ mlp, float* __restrict__ out)
{
    constexpr int PAD  = 4 * STEP;
    constexpr int PW   = W + 2*PAD;
    constexpr int PH   = H + 2*PAD;
    constexpr int HW   = H * W;
    constexpr int QUADS = HW / 4;
    constexpr int QPH   = QUADS / 2;          // quads per pixel-half
    constexpr int ITERS = (QPH + 63) / 64;
    constexpr int WINF  = 8*STEP + 4;         // window floats per (quad,ky)
    constexpr int WIN4  = WINF / 4;

    __shared__ __align__(16) float f1s[PH*PW];
    __shared__ float part[2][2][81];          // [pixel-half][frame][offset]
    __shared__ float simC[2][81];

    const int c    = blockIdx.x;
    const int b    = blockIdx.y;
    const int tid  = threadIdx.x;
    const int lane = tid & 63;
    const int wave = tid >> 6;
    const int ph   = wave / 3;     // pixel half
    const int kys  = wave % 3;     // ky triple: ky = kys*3 + {0,1,2}

    const float* f1  = pf + ((size_t)(b*TPP + TPP-1) * C + c) * HW;
    const float* f2a = pf + ((size_t)idx[b*TFF + 0] * C + c) * HW;
    const float* f2b = pf + ((size_t)idx[b*TFF + 1] * C + c) * HW;

    // stage padded f1 plane
    for (int i = tid; i < PH*PW; i += 384) {
        int y = i / PW - PAD;
        int x = i % PW - PAD;
        float val = 0.f;
        if (y >= 0 && y < H && x >= 0 && x < W) val = f1[y*W + x];
        f1s[i] = val;
    }
    __syncthreads();

    float acc[2][3][9];
    #pragma unroll
    for (int f = 0; f < 2; f++)
        #pragma unroll
        for (int j = 0; j < 3; j++)
            #pragma unroll
            for (int k = 0; k < 9; k++) acc[f][j][k] = 0.f;

    for (int it = 0; it < ITERS; it++) {
        int q = ph*QPH + it*64 + lane;
        if (q < (ph+1)*QPH) {
            int p4 = q * 4;
            int h  = p4 / W;
            int w0 = p4 % W;                  // multiple of 4 -> 16B aligned
            float4 fa = *(const float4*)(f2a + p4);
            float4 fb = *(const float4*)(f2b + p4);
            #pragma unroll
            for (int j = 0; j < 3; j++) {
                int ky = kys*3 + j;
                const float* row = &f1s[(h + PAD + (ky-4)*STEP) * PW + w0];
                float win[WINF];
                #pragma unroll
                for (int t = 0; t < WIN4; t++)
                    *(float4*)&win[t*4] = *(const float4*)&row[t*4];
                #pragma unroll
                for (int kx = 0; kx < 9; kx++) {
                    float w0v = win[kx*STEP+0], w1v = win[kx*STEP+1];
                    float w2v = win[kx*STEP+2], w3v = win[kx*STEP+3];
                    float sa = acc[0][j][kx];
                    sa = fmaf(w0v, fa.x, sa); sa = fmaf(w1v, fa.y, sa);
                    sa = fmaf(w2v, fa.z, sa); sa = fmaf(w3v, fa.w, sa);
                    acc[0][j][kx] = sa;
                    float sb = acc[1][j][kx];
                    sb = fmaf(w0v, fb.x, sb); sb = fmaf(w1v, fb.y, sb);
                    sb = fmaf(w2v, fb.z, sb); sb = fmaf(w3v, fb.w, sb);
                    acc[1][j][kx] = sb;
                }
            }
        }
    }

    // per-wave butterfly reduce; lane 0 holds the wave total
    #pragma unroll
    for (int f = 0; f < 2; f++)
        #pragma unroll
        for (int j = 0; j < 3; j++)
            #pragma unroll
            for (int kx = 0; kx < 9; kx++) {
                float v = acc[f][j][kx];
                v += __shfl_xor(v, 32);
                v += __shfl_xor(v, 16);
                v += __shfl_xor(v, 8);
                v += __shfl_xor(v, 4);
                v += __shfl_xor(v, 2);
                v += __shfl_xor(v, 1);
                if (lane == 0) part[ph][f][(kys*3 + j)*9 + kx] = v;
            }
    __syncthreads();
    if (tid < 162) {
        int f = tid / 81, k = tid % 81;
        simC[f][k] = part[0][f][k] + part[1][f][k];
    }
    __syncthreads();

    // softmax over 81 + dot with mlp weights; wave f handles frame f
    if (tid < 128) {
        int f = wave;
        float v0 = simC[f][lane];
        float v1 = (lane + 64 < 81) ? simC[f][lane + 64] : -INFINITY;
        float mx = fmaxf(v0, v1);
        #pragma unroll
        for (int m = 32; m; m >>= 1) mx = fmaxf(mx, __shfl_xor(mx, m));
        float e0 = __expf(v0 - mx);
        float e1 = (lane + 64 < 81) ? __expf(v1 - mx) : 0.f;
        float ssum = e0 + e1;
        float dsum = e0 * mlp[lane] + ((lane + 64 < 81) ? e1 * mlp[lane + 64] : 0.f);
        #pragma unroll
        for (int m = 32; m; m >>= 1) {
            ssum += __shfl_xor(ssum, m);
            dsum += __shfl_xor(dsum, m);
        }
        if (lane == 0) out[(size_t)(b*TFF + f) * C + c] = dsum / ssum;
    }
}

// ---------------------------------------------------------------------------
extern "C" void kernel_launch(void* const* d_in, const int* in_sizes, int n_in,
                              void* d_out, int out_size, void* d_ws, size_t ws_size,
                              hipStream_t stream)
{
    const float* feat0 = (const float*)d_in[0];
    const float* w0 = (const float*)d_in[1];
    const float* g0 = (const float*)d_in[2];
    const float* b0 = (const float*)d_in[3];
    const float* m0 = (const float*)d_in[4];
    const float* v0 = (const float*)d_in[5];
    const float* feat1 = (const float*)d_in[6];
    const float* w1 = (const float*)d_in[7];
    const float* g1 = (const float*)d_in[8];
    const float* b1 = (const float*)d_in[9];
    const float* m1 = (const float*)d_in[10];
    const float* v1 = (const float*)d_in[11];
    const float* feat2 = (const float*)d_in[12];
    const float* w2 = (const float*)d_in[13];
    const float* g2 = (const float*)d_in[14];
    const float* b2 = (const float*)d_in[15];
    const float* m2 = (const float*)d_in[16];
    const float* v2 = (const float*)d_in[17];
    const float* mlp = (const float*)d_in[18];
    const int* pci = (const int*)d_in[19];
    const int* fci = (const int*)d_in[20];

    float* out = (float*)d_out;

    // workspace layout
    int* idxp    = (int*)d_ws;        // 8
    int* neededp = idxp + 8;          // 16
    float* pf0 = (float*)((char*)d_ws + 256);
    float* pf1 = pf0 + (size_t)NIMG * 128 * 6400;
    float* pf2 = pf1 + (size_t)NIMG * 256 * 1600;

    idx_kernel<<<1, 64, 0, stream>>>(pci, fci, idxp, neededp);

    // conv per level (128x128 tiles)
    conv_kernel<128, 6400><<<dim3(50, 1, NIMG), 256, 0, stream>>>(
        feat0, w0, g0, b0, m0, v0, neededp, pf0);
    conv_kernel<256, 1600><<<dim3(13, 2, NIMG), 256, 0, stream>>>(
        feat1, w1, g1, b1, m1, v1, neededp, pf1);
    conv_kernel<512, 400><<<dim3(4, 4, NIMG), 256, 0, stream>>>(
        feat2, w2, g2, b2, m2, v2, neededp, pf2);

    // fused corr + softmax + mlp (one block per (b,c), both frames)
    corr_kernel<128, 80, 80, 4><<<dim3(128, BB), 384, 0, stream>>>(
        pf0, idxp, mlp, out);
    corr_kernel<256, 40, 40, 2><<<dim3(256, BB), 384, 0, stream>>>(
        pf1, idxp, mlp, out + (size_t)NF * 128);
    corr_kernel<512, 20, 20, 1><<<dim3(512, BB), 384, 0, stream>>>(
        pf2, idxp, mlp, out + (size_t)NF * (128 + 256));
}